// Round 6
// baseline (59.364 us; speedup 1.0000x reference)
//
#include <hip/hip_runtime.h>

// Involution fused kernels for MI355X (gfx950).
// x: (4,256,56,56) f32, w1: (64,256), bn(64), w2: (784,64), b2: (784)
// out: (4,256,56,56) f32
// ws: ybf16 [4][3136][64] | wprep bf16 [16][64][64] | b2pad f32 [16][64] | w1T f32 [256][64]

#define HW    3136
#define WIDE  56
#define C_IN  256
#define CR    64
#define GC    16
#define KK    49
#define BN_EPS 1e-5f

typedef __attribute__((ext_vector_type(8))) short short8;
typedef __attribute__((ext_vector_type(4))) float f32x4;
typedef __attribute__((ext_vector_type(2))) unsigned int u32x2;

__device__ __forceinline__ unsigned short f2bf(float f) {
    unsigned u = __float_as_uint(f);
    return (unsigned short)((u + 0x7FFFu + ((u >> 16) & 1u)) >> 16);   // RNE
}

// ---- Prep: w1T[c][o] f32; wprep[g][k][c] bf16 (k>=49 zero); b2pad[g][k] f32 ----
__global__ __launch_bounds__(256) void prep_kernel(
    const float* __restrict__ w1, const float* __restrict__ w2,
    const float* __restrict__ b2,
    float* __restrict__ w1T, unsigned short* __restrict__ wprep,
    float* __restrict__ b2pad)
{
    const int t = blockIdx.x * 256 + threadIdx.x;   // 0..65535
    if (t < 16384) {                                // w1T: c=t>>6, o=t&63
        const int c = t >> 6, o = t & 63;
        w1T[c * 64 + o] = w1[o * C_IN + c];
    }
    {                                               // wprep: g=t>>12, k=(t>>6)&63, c=t&63
        const int g = t >> 12, k = (t >> 6) & 63, c = t & 63;
        wprep[t] = (k < KK) ? f2bf(w2[(size_t)(g * KK + k) * CR + c]) : (unsigned short)0;
    }
    if (t < 1024) {                                 // b2pad
        const int g = t >> 6, k = t & 63;
        b2pad[t] = (k < KK) ? b2[g * KK + k] : 0.f;
    }
}

// ---- Kernel 1: y = relu(bn(w1 @ x)) -> bf16, layout [b][px][c] ----
// 800 blocks, XCD-pinned: bid -> (xcd j = bid&7, slot s = bid>>3); the 4
// og-quads (q = s&3) of tile tl = (s>>2)*8 + j run consecutively on ONE
// XCD -> the 64KB x tile is fetched from HBM once, L2-reused 4x.
__global__ __launch_bounds__(256) void conv1_bn_relu(
    const float* __restrict__ x, const float* __restrict__ w1T,
    const float* __restrict__ gamma, const float* __restrict__ beta,
    const float* __restrict__ mean, const float* __restrict__ var,
    unsigned short* __restrict__ ybf)
{
    const int bid = blockIdx.x;              // 0..799
    const int j   = bid & 7;                 // XCD (round-robin heuristic)
    const int s   = bid >> 3;                // per-XCD slot
    const int q   = s & 3;                   // og-quad
    const int tl  = (s >> 2) * 8 + j;        // tile 0..199
    if (tl >= 196) return;

    const int t    = threadIdx.x;
    const int lane = t & 63;
    const int og   = __builtin_amdgcn_readfirstlane(q * 4 + (t >> 6)); // 0..15
    const int b    = tl / 49;
    const int hw   = (tl - b * 49) * 64 + lane;

    const float* __restrict__ xb = x + (size_t)b * C_IN * HW + hw;

    float acc[4] = {0.f, 0.f, 0.f, 0.f};
#pragma unroll 8
    for (int c = 0; c < C_IN; ++c) {
        const float xv = xb[(size_t)c * HW];
        const f32x4 wv = *(const f32x4*)(w1T + c * 64 + og * 4);   // uniform -> s_load_dwordx4
#pragma unroll
        for (int u = 0; u < 4; ++u) acc[u] += wv[u] * xv;
    }

    unsigned short o4[4];
#pragma unroll
    for (int u = 0; u < 4; ++u) {
        const int o = og * 4 + u;
        const float sc = gamma[o] * rsqrtf(var[o] + BN_EPS);
        const float sh = beta[o] - mean[o] * sc;
        o4[u] = f2bf(fmaxf(acc[u] * sc + sh, 0.f));
    }
    u32x2 pack;
    pack.x = (unsigned)o4[0] | ((unsigned)o4[1] << 16);
    pack.y = (unsigned)o4[2] | ((unsigned)o4[3] << 16);
    *(u32x2*)(ybf + ((size_t)(b * HW + hw)) * 64 + og * 4) = pack;
}

// ---- Kernel 2: MFMA conv2 + vectorized involution. 4 waves / block. ----
// Block = (b, g, 64-px tile), 256 threads -> 8 blocks/CU = 32 waves/CU.
// Phase 1 (per wave q): B = y[px = q*16+l15][c], A = wprep rows; 8 MFMAs
//   -> kw[64 taps][16 px]; bias added, OOB taps zeroed -> kw_lds[k][px].
// Phase 2: thread = (pg = tid&15 -> 4 px, ch = tid>>4 -> 1 ch). Per row i:
//   3 aligned float4 x-loads cover the 12-float window; per tap j: 1
//   broadcast ds_read_b128 (kw for 4 px) + 4 FMA. Garbage edge elements
//   only ever multiply kw==0.
__global__ __launch_bounds__(256) void conv2_involution(
    const float* __restrict__ x, const unsigned short* __restrict__ ybf,
    const unsigned short* __restrict__ wprep, const float* __restrict__ b2pad,
    float* __restrict__ out)
{
    __shared__ float kw_lds[64 * 64];   // [tap][px], 16 KB

    const int tid  = threadIdx.x;
    const int lane = tid & 63;
    const int q    = __builtin_amdgcn_readfirstlane(tid >> 6);  // wave 0..3
    const int l15  = lane & 15;
    const int lg   = lane >> 4;
    const int tile = blockIdx.x;                 // 0..48
    const int g    = blockIdx.y & 15;
    const int b    = blockIdx.y >> 4;

    // ---- Phase 1: kw = W2g @ y  (this wave: pixel quadrant q) ----
    {
        const int px  = q * 16 + l15;
        const int hwp = tile * 64 + px;
        const unsigned short* yb = ybf + ((size_t)(b * HW + hwp)) * 64 + lg * 8;
        const short8 B0 = *(const short8*)(yb);
        const short8 B1 = *(const short8*)(yb + 32);

        f32x4 acc[4];
#pragma unroll
        for (int rt = 0; rt < 4; ++rt) {
            const unsigned short* ar = wprep + g * 4096 + (rt * 16 + l15) * 64 + lg * 8;
            const short8 A0 = *(const short8*)(ar);
            const short8 A1 = *(const short8*)(ar + 32);
            acc[rt] = (f32x4){0.f, 0.f, 0.f, 0.f};
            acc[rt] = __builtin_amdgcn_mfma_f32_16x16x32_bf16(A0, B0, acc[rt], 0, 0, 0);
            acc[rt] = __builtin_amdgcn_mfma_f32_16x16x32_bf16(A1, B1, acc[rt], 0, 0, 0);
        }

        const int hp = hwp / WIDE;
        const int wp = hwp - hp * WIDE;
#pragma unroll
        for (int rt = 0; rt < 4; ++rt)
#pragma unroll
            for (int r = 0; r < 4; ++r) {
                const int k  = rt * 16 + lg * 4 + r;
                const float val = acc[rt][r] + b2pad[g * 64 + k];
                const int i7 = k / 7, j7 = k - i7 * 7;
                const int rr = hp + i7 - 3, cc = wp + j7 - 3;
                const bool valid = (k < KK) & (rr >= 0) & (rr < WIDE) &
                                   (cc >= 0) & (cc < WIDE);
                kw_lds[k * 64 + px] = valid ? val : 0.f;
            }
    }
    __syncthreads();

    // ---- Phase 2: involution, 4 px x 1 ch per thread ----
    const int pg   = tid & 15;
    const int ch   = tid >> 4;                   // 0..15
    const int hw4  = tile * 64 + pg * 4;         // 4-aligned flat pixel base
    const int hrow = hw4 / WIDE;
    const int hcol = hw4 - hrow * WIDE;          // 4-aligned (56 % 4 == 0)

    const float* __restrict__ bp =
        x + ((size_t)b * C_IN + g * GC + ch) * HW;

    float acc[4] = {0.f, 0.f, 0.f, 0.f};

#pragma unroll
    for (int i = 0; i < 7; ++i) {
        const int rc    = min(max(hrow + i - 3, 0), WIDE - 1);  // v_med3
        const int basef = rc * WIDE + hcol;
        const int i0 = max(basef - 4, 0);
        const int i2 = min(basef + 4, HW - 4);

        float win[12];
        {
            const f32x4 A0 = *(const f32x4*)(bp + i0);
            const f32x4 A1 = *(const f32x4*)(bp + basef);
            const f32x4 A2 = *(const f32x4*)(bp + i2);
#pragma unroll
            for (int e = 0; e < 4; ++e) {
                win[e]     = A0[e];
                win[e + 4] = A1[e];
                win[e + 8] = A2[e];
            }
        }
#pragma unroll
        for (int jj = 0; jj < 7; ++jj) {
            const f32x4 kw4 = *(const f32x4*)&kw_lds[(i * 7 + jj) * 64 + pg * 4];
#pragma unroll
            for (int p = 0; p < 4; ++p)
                acc[p] += kw4[p] * win[p + jj + 1];   // e = 4+(p+jj-3)
        }
    }

    f32x4 st;
#pragma unroll
    for (int p = 0; p < 4; ++p) st[p] = acc[p];
    *(f32x4*)(out + ((size_t)b * C_IN + g * GC + ch) * HW + hw4) = st;
}

extern "C" void kernel_launch(void* const* d_in, const int* in_sizes, int n_in,
                              void* d_out, int out_size, void* d_ws, size_t ws_size,
                              hipStream_t stream) {
    const float* x     = (const float*)d_in[0];
    const float* w1    = (const float*)d_in[1];
    const float* gamma = (const float*)d_in[2];
    const float* beta  = (const float*)d_in[3];
    const float* mean  = (const float*)d_in[4];
    const float* var   = (const float*)d_in[5];
    const float* w2    = (const float*)d_in[6];
    const float* b2    = (const float*)d_in[7];
    float* out = (float*)d_out;

    char* ws = (char*)d_ws;
    unsigned short* ybf   = (unsigned short*)(ws);             // 1,605,632 B
    unsigned short* wprep = (unsigned short*)(ws + 1605632);   //   131,072 B
    float*          b2pad = (float*)(ws + 1736704);            //     4,096 B
    float*          w1T   = (float*)(ws + 1740800);            //    65,536 B

    prep_kernel<<<dim3(256), dim3(256), 0, stream>>>(w1, w2, b2, w1T, wprep, b2pad);
    conv1_bn_relu<<<dim3(800), dim3(256), 0, stream>>>(x, w1T, gamma, beta, mean, var, ybf);
    conv2_involution<<<dim3(49, 64), dim3(256), 0, stream>>>(x, ybf, wprep, b2pad, out);
}